// Round 1
// baseline (194.699 us; speedup 1.0000x reference)
//
#include <hip/hip_runtime.h>

#define BATCH   1024
#define IN      1024
#define OUT     40960
#define KF      7
#define BT      8            // batch rows per block (2 interleaved groups of 4)
#define NO      4            // output columns per thread
#define THREADS 256
#define OTILE   (THREADS * NO)   // 1024 outputs per block

// y[b, o] = sum_k vals[o,k] * x[b, idx[o,k]]
//
// Layout trick: LDS holds x for 8 batch rows, interleaved by groups of 4:
//   xs[g*IN*4 + i*4 + r] = x[b0 + 4*g + r][i],  g in {0,1}, r in {0..3}
// so one ds_read_b128 at i*16 returns the gathered value for 4 batch rows.
// This cuts the LDS gather instruction count 4x vs scalar ds_read_b32,
// bringing the LDS pipe (~24us) to parity with the HBM write floor (~27us).
__global__ __launch_bounds__(THREADS, 4)
void sparse_proj(const float* __restrict__ x, const float* __restrict__ vals,
                 const int* __restrict__ idx, float* __restrict__ y)
{
    __shared__ float xs[2 * IN * 4];   // 32 KB -> up to 5 blocks/CU (LDS-limited)

    const int t     = threadIdx.x;
    const int b0    = blockIdx.y * BT;
    const int obase = blockIdx.x * OTILE + t;

    // ---- stage x tile (8 rows x 1024 cols) into LDS, row-interleaved ----
    // Threads 0..127 build group 0 (rows b0..b0+3), 128..255 group 1.
    // Per (thread, j): 4 coalesced scalar global loads (one per row, lanes
    // have consecutive i) -> one conflict-free ds_write_b128.
    {
        const int g  = t >> 7;          // 0..1
        const int i0 = t & 127;
        const float* xb = x + (size_t)(b0 + 4 * g) * IN;
        float* dstg = &xs[g * (IN * 4)];
#pragma unroll
        for (int j = 0; j < 8; ++j) {
            const int i = i0 + j * 128;
            float4 f;
            f.x = xb[0 * IN + i];
            f.y = xb[1 * IN + i];
            f.z = xb[2 * IN + i];
            f.w = xb[3 * IN + i];
            *(float4*)&dstg[i * 4] = f;
        }
    }
    __syncthreads();

    float acc[NO][BT];
#pragma unroll
    for (int no = 0; no < NO; ++no)
#pragma unroll
        for (int r = 0; r < BT; ++r) acc[no][r] = 0.0f;

#pragma unroll
    for (int no = 0; no < NO; ++no) {
        const int o = obase + no * THREADS;
        const int*   ip = idx  + (size_t)o * KF;
        const float* vp = vals + (size_t)o * KF;
#pragma unroll
        for (int k = 0; k < KF; ++k) {
            const int   i = ip[k];          // L2-resident (2.3 MB total)
            const float v = vp[k];
            const float4 a = *(const float4*)&xs[i * 4];            // rows b0..b0+3
            const float4 b = *(const float4*)&xs[IN * 4 + i * 4];   // rows b0+4..b0+7
            acc[no][0] = fmaf(v, a.x, acc[no][0]);
            acc[no][1] = fmaf(v, a.y, acc[no][1]);
            acc[no][2] = fmaf(v, a.z, acc[no][2]);
            acc[no][3] = fmaf(v, a.w, acc[no][3]);
            acc[no][4] = fmaf(v, b.x, acc[no][4]);
            acc[no][5] = fmaf(v, b.y, acc[no][5]);
            acc[no][6] = fmaf(v, b.z, acc[no][6]);
            acc[no][7] = fmaf(v, b.w, acc[no][7]);
        }
    }

    // ---- store: coalesced per (row, no); nontemporal so the 168 MB write
    // stream does not evict L2-resident x / idx / vals ----
#pragma unroll
    for (int r = 0; r < BT; ++r) {
        float* yr = y + (size_t)(b0 + r) * OUT;
#pragma unroll
        for (int no = 0; no < NO; ++no) {
            __builtin_nontemporal_store(acc[no][r], &yr[obase + no * THREADS]);
        }
    }
}

extern "C" void kernel_launch(void* const* d_in, const int* in_sizes, int n_in,
                              void* d_out, int out_size, void* d_ws, size_t ws_size,
                              hipStream_t stream) {
    const float* x    = (const float*)d_in[0];   // [1024, 1024] fp32
    const float* vals = (const float*)d_in[1];   // [40960, 7]  fp32
    const int*   idx  = (const int*)d_in[2];     // [40960, 7]  int32
    float*       y    = (float*)d_out;           // [1024, 40960] fp32

    dim3 grid(OUT / OTILE, BATCH / BT);          // (40, 128) = 5120 blocks
    sparse_proj<<<grid, dim3(THREADS), 0, stream>>>(x, vals, idx, y);
}